// Round 5
// baseline (1613.190 us; speedup 1.0000x reference)
//
#include <hip/hip_runtime.h>
#include <math.h>
#include <stdint.h>

// Problem constants (fixed by setup_inputs)
#define S_DIM 128
#define B_DIM 256
#define L_DIM 512
#define K_DIM 8
#define T_IN  16
#define STEPS 103                      // 128 - 16 - (8 + 0 + 1)
#define DENOM (K_DIM * STEPS * B_DIM)  // 210944

#define PS_LD 136                      // Ps leading dim (128 + 8 pad, 16B-aligned rows)

typedef __attribute__((ext_vector_type(8))) short short8;  // 8 bf16 (MFMA A/B frag)
typedef __attribute__((ext_vector_type(4))) float f32x4;   // MFMA C/D frag

// round-to-nearest-even fp32 -> bf16
__device__ __forceinline__ short f2bf(float f) {
    unsigned u = __float_as_uint(f);
    u += 0x7FFFu + ((u >> 16) & 1u);
    return (short)(u >> 16);
}

// async global->LDS, 16B per lane; LDS dest = wave-uniform base + lane*16
__device__ __forceinline__ void load_lds16(const void* g, void* l) {
    __builtin_amdgcn_global_load_lds(
        (const __attribute__((address_space(1))) unsigned*)g,
        (__attribute__((address_space(3))) unsigned*)l, 16, 0, 0);
}

// One fused fp32->bf16 convert over all three inputs (grid-stride, float4)
#define ENC4 ((S_DIM * B_DIM * L_DIM) / 4)          // 4,194,304
#define CTX4 ((STEPS * B_DIM * L_DIM) / 4)          // 3,375,104
#define WK4  ((K_DIM * L_DIM * L_DIM) / 4)          //   524,288
__global__ void convert_all(const float* __restrict__ enc_in, const float* __restrict__ ctx_in,
                            const float* __restrict__ wk_in, short* __restrict__ enc_out,
                            short* __restrict__ ctx_out, short* __restrict__ wk_out) {
    for (int i = blockIdx.x * blockDim.x + threadIdx.x; i < ENC4 + CTX4 + WK4;
         i += gridDim.x * blockDim.x) {
        const float4* src; short4* dst; int j;
        if (i < ENC4)             { src = (const float4*)enc_in; dst = (short4*)enc_out; j = i; }
        else if (i < ENC4 + CTX4) { src = (const float4*)ctx_in; dst = (short4*)ctx_out; j = i - ENC4; }
        else                      { src = (const float4*)wk_in;  dst = (short4*)wk_out;  j = i - ENC4 - CTX4; }
        const float4 v = src[j];
        short4 o;
        o.x = f2bf(v.x); o.y = f2bf(v.y); o.z = f2bf(v.z); o.w = f2bf(v.w);
        dst[j] = o;
    }
}

// ---------------------------------------------------------------------------
// Fully fused CPC kernel. Grid (103, 8): block (s, k). 512 thr = 8 waves.
// Per m-chunk (128 of 512):
//   Phase A: P[c][m] = sum_l ctx_s[c][l]*Wk_k[m][l] for m in chunk (256x128),
//     staged LDS GEMM (BK=64, global_load_lds w=16, XOR chunk swizzle).
//     MFMA M-dim = m, N-dim = c so each lane holds 4 contiguous m -> short4
//     bf16 writes into Ps[c][m] (LD=136, conflict-free).
//   Phase B: sim[b][c] += enc_s[b][m-chunk] . Ps[c][m-chunk]; enc frags
//     register-direct from global (L3-hot), Ps frags from LDS.
// Epilogue: in-register row softmax stats (quad-local shuffles), diag accum
// (1 atomic/block), per-column argmax merged via LDS then 256 atomicMax.
// pred NEVER touches HBM.
// ---------------------------------------------------------------------------
__global__ __launch_bounds__(512, 1)
void fused_cpc(const short* __restrict__ encbf, const short* __restrict__ ctxbf,
               const short* __restrict__ wkbf, unsigned long long* __restrict__ col_best,
               float* __restrict__ diag_accum) {
    __shared__ short ctxs[256 * 64];               // 32 KB
    __shared__ short wks[128 * 64];                // 16 KB
    __shared__ short Ps[256 * PS_LD];              // 69.6 KB
    __shared__ unsigned long long cb[8][256];      // 16 KB
    __shared__ float dred[8];

    const int s = blockIdx.x, k = blockIdx.y;
    const int t = threadIdx.x, w = t >> 6, lane = t & 63;
    const int quad = lane >> 4, l15 = lane & 15;
    const int wm = w & 1, wc = w >> 1;             // phase-A wave grid: 2(m) x 4(c)
    const int rl8 = lane >> 3, ch8 = lane & 7;     // staging split: 8 rows x 8 chunks

    const short* ctx_s = ctxbf + (size_t)s * B_DIM * L_DIM;
    const short* wk_k  = wkbf + (size_t)k * L_DIM * L_DIM;
    const short* enc_s = encbf + (size_t)(T_IN + 1 + k + s) * B_DIM * L_DIM;

    f32x4 Sacc[2][16] = {};                        // sim: rows w*32+bi*16+quad*4+r, cols cj*16+l15

    for (int mc = 0; mc < 4; mc++) {
        const int m0 = mc * 128;
        f32x4 Pacc[4][4] = {};                     // P^T tile: m = wm*64+mf*16+quad*4+r, c = wc*64+cj*16+l15
        for (int lt = 0; lt < 8; lt++) {
            const int l0 = lt * 64;
            #pragma unroll
            for (int q = 0; q < 4; q++) {          // ctxs: 256 rows x 64, 4 issues/thread
                const int r = w * 32 + q * 8 + rl8;
                const int cidx = ch8 ^ (r & 7);
                load_lds16(ctx_s + (size_t)r * L_DIM + l0 + cidx * 8,
                           &ctxs[(w * 32 + q * 8) * 64]);
            }
            #pragma unroll
            for (int q = 0; q < 2; q++) {          // wks: 128 rows x 64, 2 issues/thread
                const int r = w * 16 + q * 8 + rl8;
                const int cidx = ch8 ^ (r & 7);
                load_lds16(wk_k + (size_t)(m0 + r) * L_DIM + l0 + cidx * 8,
                           &wks[(w * 16 + q * 8) * 64]);
            }
            __syncthreads();
            #pragma unroll
            for (int kt = 0; kt < 2; kt++) {
                short8 a[4], b[4];
                #pragma unroll
                for (int mf = 0; mf < 4; mf++) {
                    const int rm = wm * 64 + mf * 16 + l15;
                    a[mf] = *(const short8*)&wks[rm * 64 + ((kt * 4 + quad) ^ (rm & 7)) * 8];
                }
                #pragma unroll
                for (int cj = 0; cj < 4; cj++) {
                    const int rc = wc * 64 + cj * 16 + l15;
                    b[cj] = *(const short8*)&ctxs[rc * 64 + ((kt * 4 + quad) ^ (rc & 7)) * 8];
                }
                #pragma unroll
                for (int mf = 0; mf < 4; mf++)
                    #pragma unroll
                    for (int cj = 0; cj < 4; cj++)
                        Pacc[mf][cj] = __builtin_amdgcn_mfma_f32_16x16x32_bf16(
                            a[mf], b[cj], Pacc[mf][cj], 0, 0, 0);
            }
            __syncthreads();
        }
        // write P chunk to Ps[c][m] as bf16: lane has 4 contiguous m (quad*4+r)
        #pragma unroll
        for (int mf = 0; mf < 4; mf++)
            #pragma unroll
            for (int cj = 0; cj < 4; cj++) {
                const int c  = wc * 64 + cj * 16 + l15;
                const int ml = wm * 64 + mf * 16 + quad * 4;
                short4 o;
                o.x = f2bf(Pacc[mf][cj][0]); o.y = f2bf(Pacc[mf][cj][1]);
                o.z = f2bf(Pacc[mf][cj][2]); o.w = f2bf(Pacc[mf][cj][3]);
                *(short4*)&Ps[c * PS_LD + ml] = o;
            }
        __syncthreads();
        // Phase B: sim accumulation over this m-chunk (K=128 -> 4 kt2)
        #pragma unroll
        for (int kt2 = 0; kt2 < 4; kt2++) {
            short8 a[2];
            #pragma unroll
            for (int bi = 0; bi < 2; bi++) {
                const int brow = w * 32 + bi * 16 + l15;
                a[bi] = *(const short8*)(enc_s + (size_t)brow * L_DIM + m0 + kt2 * 32 + quad * 8);
            }
            #pragma unroll
            for (int cj = 0; cj < 16; cj++) {
                const short8 bb = *(const short8*)&Ps[(cj * 16 + l15) * PS_LD + kt2 * 32 + quad * 8];
                #pragma unroll
                for (int bi = 0; bi < 2; bi++)
                    Sacc[bi][cj] = __builtin_amdgcn_mfma_f32_16x16x32_bf16(
                        a[bi], bb, Sacc[bi][cj], 0, 0, 0);
            }
        }
        // no barrier needed: next mc's staging writes ctxs/wks (not Ps), and its
        // own pre-read barrier orders them; Ps rewrite is 8 barriers away.
    }

    // ---- epilogue. Lane's sim values: rows b = w*32+bi*16+quad*4+r, cols c = cj*16+l15.
    // All 16 lanes of a quad share the same 8 rows -> row stats via xor 1,2,4,8.
    float lse[2][4];
    #pragma unroll
    for (int bi = 0; bi < 2; bi++)
        #pragma unroll
        for (int r = 0; r < 4; r++) {
            float m = Sacc[bi][0][r];
            #pragma unroll
            for (int cj = 1; cj < 16; cj++) m = fmaxf(m, Sacc[bi][cj][r]);
            #pragma unroll
            for (int off = 1; off < 16; off <<= 1) m = fmaxf(m, __shfl_xor(m, off, 64));
            float sum = 0.f;
            #pragma unroll
            for (int cj = 0; cj < 16; cj++) sum += expf(Sacc[bi][cj][r] - m);
            #pragma unroll
            for (int off = 1; off < 16; off <<= 1) sum += __shfl_xor(sum, off, 64);
            lse[bi][r] = m + logf(sum);
        }

    // diag logp: c == b requires cj == w*2+bi and l15 == quad*4+r
    {
        float dv = 0.f;
        #pragma unroll
        for (int bi = 0; bi < 2; bi++)
            #pragma unroll
            for (int r = 0; r < 4; r++)
                if (l15 == quad * 4 + r) dv += Sacc[bi][w * 2 + bi][r] - lse[bi][r];
        #pragma unroll
        for (int off = 1; off < 64; off <<= 1) dv += __shfl_xor(dv, off, 64);
        if (lane == 0) dred[w] = dv;
    }

    // per-column argmax over this wave's 32 rows (packed u64, first-index ties)
    #pragma unroll
    for (int cj = 0; cj < 16; cj++) {
        unsigned long long best = 0;
        #pragma unroll
        for (int bi = 0; bi < 2; bi++)
            #pragma unroll
            for (int r = 0; r < 4; r++) {
                const int b = w * 32 + bi * 16 + quad * 4 + r;
                const float v = Sacc[bi][cj][r] - lse[bi][r];
                unsigned int fb = __float_as_uint(v);
                fb = (fb & 0x80000000u) ? ~fb : (fb | 0x80000000u);
                const unsigned long long p =
                    ((unsigned long long)fb << 32) | (unsigned long long)(255 - b);
                if (p > best) best = p;
            }
        unsigned long long o;
        o = __shfl_xor(best, 16, 64); if (o > best) best = o;
        o = __shfl_xor(best, 32, 64); if (o > best) best = o;
        if (quad == 0) cb[w][cj * 16 + l15] = best;
    }
    __syncthreads();
    if (t < 256) {
        unsigned long long best = cb[0][t];
        #pragma unroll
        for (int w2 = 1; w2 < 8; w2++) if (cb[w2][t] > best) best = cb[w2][t];
        atomicMax(&col_best[((size_t)k * STEPS + s) * B_DIM + t], best);
    }
    if (t == 0) {
        float dv = 0.f;
        #pragma unroll
        for (int i = 0; i < 8; i++) dv += dred[i];
        atomicAdd(diag_accum, dv);
    }
}

__global__ void count_correct(const unsigned long long* __restrict__ col_best,
                              int* __restrict__ correct_accum) {
    __shared__ int red[256];
    const int t = threadIdx.x;
    int cnt = 0;
    for (int i = blockIdx.x * 256 + t; i < DENOM; i += gridDim.x * 256) {
        const int c = i & (B_DIM - 1);
        const int b = 255 - (int)(col_best[i] & 0xFFFFFFFFull);
        cnt += (b == c) ? 1 : 0;
    }
    red[t] = cnt;
    __syncthreads();
    for (int off = 128; off > 0; off >>= 1) {
        if (t < off) red[t] += red[t + off];
        __syncthreads();
    }
    if (t == 0) atomicAdd(correct_accum, red[0]);
}

__global__ void finalize(const int* __restrict__ correct_accum,
                         const float* __restrict__ diag_accum,
                         float* __restrict__ out) {
    const float denom = (float)DENOM;
    out[0] = (float)(*correct_accum) / denom;   // accuracy
    out[1] = -(*diag_accum) / denom;            // loss
}

extern "C" void kernel_launch(void* const* d_in, const int* in_sizes, int n_in,
                              void* d_out, int out_size, void* d_ws, size_t ws_size,
                              hipStream_t stream) {
    const float* encoded_x = (const float*)d_in[0];
    const float* context   = (const float*)d_in[1];
    const float* Wk        = (const float*)d_in[2];
    float* out = (float*)d_out;

    const size_t enc_elems = (size_t)S_DIM * B_DIM * L_DIM;    // 16,777,216
    const size_t ctx_elems = (size_t)STEPS * B_DIM * L_DIM;    // 13,500,416
    const size_t wk_elems  = (size_t)K_DIM * L_DIM * L_DIM;    //  2,097,152

    char* ws = (char*)d_ws;
    short* encbf = (short*)ws;                                          // 33.6 MB
    short* ctxbf = (short*)(ws + enc_elems * 2);                        // 27.0 MB
    short* wkbf  = (short*)(ws + (enc_elems + ctx_elems) * 2);          //  4.2 MB
    const size_t off = (enc_elems + ctx_elems + wk_elems) * 2;
    unsigned long long* col_best = (unsigned long long*)(ws + off);     // 1.69 MB
    float* diag_accum    = (float*)(ws + off + (size_t)DENOM * 8);
    int*   correct_accum = (int*)  (ws + off + (size_t)DENOM * 8 + 4);

    hipMemsetAsync(col_best, 0, (size_t)DENOM * 8 + 16, stream);
    convert_all<<<2048, 256, 0, stream>>>(encoded_x, context + (size_t)T_IN * B_DIM * L_DIM,
                                          Wk, encbf, ctxbf, wkbf);

    fused_cpc<<<dim3(STEPS, K_DIM), 512, 0, stream>>>(encbf, ctxbf, wkbf,
                                                      col_best, diag_accum);
    count_correct<<<64, 256, 0, stream>>>(col_best, correct_accum);
    finalize<<<1, 1, 0, stream>>>(correct_accum, diag_accum, out);
}

// Round 6
// 648.631 us; speedup vs baseline: 2.4871x; 2.4871x over previous
//
#include <hip/hip_runtime.h>
#include <math.h>
#include <stdint.h>

// Problem constants (fixed by setup_inputs)
#define S_DIM 128
#define B_DIM 256
#define L_DIM 512
#define K_DIM 8
#define T_IN  16
#define STEPS 103                      // 128 - 16 - (8 + 0 + 1)
#define DENOM (K_DIM * STEPS * B_DIM)  // 210944
#define PRED_K ((size_t)STEPS * B_DIM * L_DIM)   // elems per k slab (13,500,416)

typedef __attribute__((ext_vector_type(8))) short short8;  // 8 bf16 (MFMA A/B frag)
typedef __attribute__((ext_vector_type(4))) float f32x4;   // MFMA C/D frag

// round-to-nearest-even fp32 -> bf16
__device__ __forceinline__ short f2bf(float f) {
    unsigned u = __float_as_uint(f);
    u += 0x7FFFu + ((u >> 16) & 1u);
    return (short)(u >> 16);
}

// async global->LDS, 16B per lane; LDS dest = wave-uniform base + lane*16
__device__ __forceinline__ void load_lds16(const void* g, void* l) {
    __builtin_amdgcn_global_load_lds(
        (const __attribute__((address_space(1))) unsigned*)g,
        (__attribute__((address_space(3))) unsigned*)l, 16, 0, 0);
}

// One fused fp32->bf16 convert over all three inputs (grid-stride, float4)
#define ENC4 ((S_DIM * B_DIM * L_DIM) / 4)          // 4,194,304
#define CTX4 ((STEPS * B_DIM * L_DIM) / 4)          // 3,375,104
#define WK4  ((K_DIM * L_DIM * L_DIM) / 4)          //   524,288
__global__ void convert_all(const float* __restrict__ enc_in, const float* __restrict__ ctx_in,
                            const float* __restrict__ wk_in, short* __restrict__ enc_out,
                            short* __restrict__ ctx_out, short* __restrict__ wk_out) {
    for (int i = blockIdx.x * blockDim.x + threadIdx.x; i < ENC4 + CTX4 + WK4;
         i += gridDim.x * blockDim.x) {
        const float4* src; short4* dst; int j;
        if (i < ENC4)             { src = (const float4*)enc_in; dst = (short4*)enc_out; j = i; }
        else if (i < ENC4 + CTX4) { src = (const float4*)ctx_in; dst = (short4*)ctx_out; j = i - ENC4; }
        else                      { src = (const float4*)wk_in;  dst = (short4*)wk_out;  j = i - ENC4 - CTX4; }
        const float4 v = src[j];
        short4 o;
        o.x = f2bf(v.x); o.y = f2bf(v.y); o.z = f2bf(v.z); o.w = f2bf(v.w);
        dst[j] = o;
    }
}

// ---------------------------------------------------------------------------
// bf16 MFMA GEMM (NT), k-batched: grid (206, 4g). bn -> (kin = bn>>2, cn =
// bn&3). C slab kin is per-k contiguous (26368 x 512, ldc 512).
// 128x128 tile, BK=32, 4 waves 2x2, 4x4 16x16x32 frags. global_load_lds(16B)
// with XOR chunk swizzle (verified rounds 2/4, absmax 0, 0 bank conflicts).
// ---------------------------------------------------------------------------
__global__ __launch_bounds__(256)
void gemm_bf16(const short* __restrict__ A, const short* __restrict__ W,
               short* __restrict__ C) {
    __shared__ short As[128 * 32];   // 8 KB, [row][32], chunk-swizzled
    __shared__ short Bs[128 * 32];   // 8 KB
    const int bm = blockIdx.x;
    const int kin = blockIdx.y >> 2, cn = blockIdx.y & 3;
    const int t = threadIdx.x;
    const int w = t >> 6, lane = t & 63, quad = lane >> 4, l15 = lane & 15;
    const int wm = w & 1, wn = w >> 1;
    const int rloc = lane >> 2, ko = lane & 3;

    const short* Ab = A + (size_t)bm * 128 * L_DIM;
    const short* Wb = W + ((size_t)kin * L_DIM + cn * 128) * L_DIM;
    short* Ck = C + kin * PRED_K;

    f32x4 acc[4][4] = {};

    for (int kt = 0; kt < L_DIM; kt += 32) {
        #pragma unroll
        for (int j = 0; j < 2; j++) {                 // each wave stages 32 rows of A and B
            const int rb = w * 32 + j * 16;
            const int row = rb + rloc;
            const int ch = ko ^ ((row >> 1) & 3);
            load_lds16(Ab + (size_t)row * L_DIM + kt + ch * 8, &As[rb * 32]);
            load_lds16(Wb + (size_t)row * L_DIM + kt + ch * 8, &Bs[rb * 32]);
        }
        __syncthreads();
        short8 a[4], b[4];
        #pragma unroll
        for (int i = 0; i < 4; i++) {
            const int m = wm * 64 + i * 16 + l15;
            a[i] = *(const short8*)&As[m * 32 + (quad ^ ((m >> 1) & 3)) * 8];
            const int n = wn * 64 + i * 16 + l15;
            b[i] = *(const short8*)&Bs[n * 32 + (quad ^ ((n >> 1) & 3)) * 8];
        }
        #pragma unroll
        for (int i = 0; i < 4; i++)
            #pragma unroll
            for (int j = 0; j < 4; j++)
                acc[i][j] = __builtin_amdgcn_mfma_f32_16x16x32_bf16(a[i], b[j], acc[i][j], 0, 0, 0);
        __syncthreads();
    }
    // C/D layout: col = lane&15, row = quad*4 + reg  [verified]
    #pragma unroll
    for (int i = 0; i < 4; i++)
        #pragma unroll
        for (int r = 0; r < 4; r++) {
            const int row = bm * 128 + wm * 64 + i * 16 + quad * 4 + r;
            short* Cr = Ck + (size_t)row * L_DIM + cn * 128 + wn * 64 + l15;
            #pragma unroll
            for (int j = 0; j < 4; j++)
                Cr[j * 16] = f2bf(acc[i][j][r]);
        }
}

// ---------------------------------------------------------------------------
// Fused sim + log-softmax + argmax, k-batched. Grid (103, 2, g): block
// (s, bt, kin) covers rows b = bt*128..+127, all 256 cols, k = k0 + kin.
// 512 thr = 8 waves (2m x 4n), wave tile 64x64. Barrier-free register-direct
// K-loop + in-register epilogue (verified rounds 3/4, absmax 0).
//   sim[b][c] = sum_l encbf[(T_IN+1+k+s)*256+b][l] * pred_kin[s*256+c][l]
// ---------------------------------------------------------------------------
__global__ __launch_bounds__(512)
void sim_phase(const short* __restrict__ encbf, const short* __restrict__ pred,
               const int k0, unsigned long long* __restrict__ col_best,
               float* __restrict__ diag_accum) {
    __shared__ float pm[128][4];    // per-(row, nj-wave) max partials
    __shared__ float ps[128][4];    // per-(row, nj-wave) expsum partials
    __shared__ float dred[8];       // per-wave diag partials
    const int s = blockIdx.x, bt = blockIdx.y, kin = blockIdx.z;
    const int k = k0 + kin;
    const int t = threadIdx.x, w = t >> 6, lane = t & 63;
    const int quad = lane >> 4, l15 = lane & 15;
    const int mi = w & 1, nj = w >> 1;

    const short* ap[4]; const short* bp[4];
    #pragma unroll
    for (int i = 0; i < 4; i++) {
        const int erow = (T_IN + 1 + k + s) * B_DIM + bt * 128 + mi * 64 + i * 16 + l15;
        ap[i] = encbf + (size_t)erow * L_DIM + quad * 8;
        const int prow = s * B_DIM + nj * 64 + i * 16 + l15;
        bp[i] = pred + kin * PRED_K + (size_t)prow * L_DIM + quad * 8;
    }

    f32x4 acc[4][4] = {};
    short8 a[2][4], b[2][4];
    #pragma unroll
    for (int i = 0; i < 4; i++) { a[0][i] = *(const short8*)ap[i]; b[0][i] = *(const short8*)bp[i]; }

    #pragma unroll
    for (int kk = 0; kk < 16; kk++) {
        const int cur = kk & 1, nxt = cur ^ 1;
        if (kk < 15) {
            #pragma unroll
            for (int i = 0; i < 4; i++) {
                a[nxt][i] = *(const short8*)(ap[i] + (kk + 1) * 32);
                b[nxt][i] = *(const short8*)(bp[i] + (kk + 1) * 32);
            }
        }
        #pragma unroll
        for (int i = 0; i < 4; i++)
            #pragma unroll
            for (int j = 0; j < 4; j++)
                acc[i][j] = __builtin_amdgcn_mfma_f32_16x16x32_bf16(a[cur][i], b[cur][j], acc[i][j], 0, 0, 0);
    }
    // lane holds acc[i][j][r] = sim[mi*64+i*16+quad*4+r (local row)][nj*64+j*16+l15]

    // ---- E1: row max over 256 cols ----
    float rm[4][4];
    #pragma unroll
    for (int i = 0; i < 4; i++)
        #pragma unroll
        for (int r = 0; r < 4; r++) {
            float m = acc[i][0][r];
            #pragma unroll
            for (int j = 1; j < 4; j++) m = fmaxf(m, acc[i][j][r]);
            rm[i][r] = m;
        }
    #pragma unroll
    for (int off = 1; off < 16; off <<= 1)
        #pragma unroll
        for (int i = 0; i < 4; i++)
            #pragma unroll
            for (int r = 0; r < 4; r++)
                rm[i][r] = fmaxf(rm[i][r], __shfl_xor(rm[i][r], off, 64));
    if (l15 == 0)
        #pragma unroll
        for (int i = 0; i < 4; i++)
            #pragma unroll
            for (int r = 0; r < 4; r++)
                pm[mi * 64 + i * 16 + quad * 4 + r][nj] = rm[i][r];
    __syncthreads();

    float mrow[4][4];
    #pragma unroll
    for (int i = 0; i < 4; i++)
        #pragma unroll
        for (int r = 0; r < 4; r++) {
            const f32x4 v = *(const f32x4*)pm[mi * 64 + i * 16 + quad * 4 + r];
            mrow[i][r] = fmaxf(fmaxf(v[0], v[1]), fmaxf(v[2], v[3]));
        }

    // ---- E2: row sum of exp ----
    float rs[4][4];
    #pragma unroll
    for (int i = 0; i < 4; i++)
        #pragma unroll
        for (int r = 0; r < 4; r++) {
            float sum = 0.f;
            #pragma unroll
            for (int j = 0; j < 4; j++) sum += expf(acc[i][j][r] - mrow[i][r]);
            rs[i][r] = sum;
        }
    #pragma unroll
    for (int off = 1; off < 16; off <<= 1)
        #pragma unroll
        for (int i = 0; i < 4; i++)
            #pragma unroll
            for (int r = 0; r < 4; r++)
                rs[i][r] += __shfl_xor(rs[i][r], off, 64);
    if (l15 == 0)
        #pragma unroll
        for (int i = 0; i < 4; i++)
            #pragma unroll
            for (int r = 0; r < 4; r++)
                ps[mi * 64 + i * 16 + quad * 4 + r][nj] = rs[i][r];
    __syncthreads();

    float lse[4][4];
    #pragma unroll
    for (int i = 0; i < 4; i++)
        #pragma unroll
        for (int r = 0; r < 4; r++) {
            const f32x4 v = *(const f32x4*)ps[mi * 64 + i * 16 + quad * 4 + r];
            lse[i][r] = mrow[i][r] + logf(v[0] + v[1] + v[2] + v[3]);
        }

    // ---- E3: column argmax (packed u64: ordered-float<<32 | (255-b)) ----
    #pragma unroll
    for (int j = 0; j < 4; j++) {
        unsigned long long best = 0;
        #pragma unroll
        for (int i = 0; i < 4; i++)
            #pragma unroll
            for (int r = 0; r < 4; r++) {
                const int grow = bt * 128 + mi * 64 + i * 16 + quad * 4 + r;
                const float v = acc[i][j][r] - lse[i][r];
                unsigned int fb = __float_as_uint(v);
                fb = (fb & 0x80000000u) ? ~fb : (fb | 0x80000000u);
                const unsigned long long p =
                    ((unsigned long long)fb << 32) | (unsigned long long)(255 - grow);
                if (p > best) best = p;          // packed compare: ties -> smallest b
            }
        unsigned long long o;
        o = __shfl_xor(best, 16, 64); if (o > best) best = o;
        o = __shfl_xor(best, 32, 64); if (o > best) best = o;
        if (quad == 0)
            atomicMax(&col_best[((size_t)k * STEPS + s) * B_DIM + nj * 64 + j * 16 + l15], best);
    }

    // ---- diag logp: 1 atomic per block ----
    {
        float dv = 0.f;
        #pragma unroll
        for (int i = 0; i < 4; i++)
            #pragma unroll
            for (int j = 0; j < 4; j++)
                #pragma unroll
                for (int r = 0; r < 4; r++) {
                    const int grow = bt * 128 + mi * 64 + i * 16 + quad * 4 + r;
                    const int c = nj * 64 + j * 16 + l15;
                    if (grow == c) dv += acc[i][j][r] - lse[i][r];
                }
        #pragma unroll
        for (int off = 1; off < 64; off <<= 1) dv += __shfl_xor(dv, off, 64);
        if (lane == 0) dred[w] = dv;
    }
    __syncthreads();
    if (t == 0) {
        float dv = 0.f;
        #pragma unroll
        for (int i = 0; i < 8; i++) dv += dred[i];
        atomicAdd(diag_accum, dv);
    }
}

__global__ void count_correct(const unsigned long long* __restrict__ col_best,
                              int* __restrict__ correct_accum) {
    __shared__ int red[256];
    const int t = threadIdx.x;
    int cnt = 0;
    for (int i = blockIdx.x * 256 + t; i < DENOM; i += gridDim.x * 256) {
        const int c = i & (B_DIM - 1);
        const int b = 255 - (int)(col_best[i] & 0xFFFFFFFFull);
        cnt += (b == c) ? 1 : 0;
    }
    red[t] = cnt;
    __syncthreads();
    for (int off = 128; off > 0; off >>= 1) {
        if (t < off) red[t] += red[t + off];
        __syncthreads();
    }
    if (t == 0) atomicAdd(correct_accum, red[0]);
}

__global__ void finalize(const int* __restrict__ correct_accum,
                         const float* __restrict__ diag_accum,
                         float* __restrict__ out) {
    const float denom = (float)DENOM;
    out[0] = (float)(*correct_accum) / denom;   // accuracy
    out[1] = -(*diag_accum) / denom;            // loss
}

extern "C" void kernel_launch(void* const* d_in, const int* in_sizes, int n_in,
                              void* d_out, int out_size, void* d_ws, size_t ws_size,
                              hipStream_t stream) {
    const float* encoded_x = (const float*)d_in[0];
    const float* context   = (const float*)d_in[1];
    const float* Wk        = (const float*)d_in[2];
    float* out = (float*)d_out;

    const size_t enc_elems = (size_t)S_DIM * B_DIM * L_DIM;    // 16,777,216
    const size_t ctx_elems = (size_t)STEPS * B_DIM * L_DIM;    // 13,500,416
    const size_t wk_elems  = (size_t)K_DIM * L_DIM * L_DIM;    //  2,097,152
    const size_t pred_k_bytes = ctx_elems * 2;                 // 27.0 MB per k

    char* ws = (char*)d_ws;
    short* encbf = (short*)ws;                                          // 33.6 MB
    short* ctxbf = (short*)(ws + enc_elems * 2);                        // 27.0 MB
    short* wkbf  = (short*)(ws + (enc_elems + ctx_elems) * 2);          //  4.2 MB
    const size_t off = (enc_elems + ctx_elems + wk_elems) * 2;
    unsigned long long* col_best = (unsigned long long*)(ws + off);     // 1.69 MB
    float* diag_accum    = (float*)(ws + off + (size_t)DENOM * 8);
    int*   correct_accum = (int*)  (ws + off + (size_t)DENOM * 8 + 4);
    const size_t fixed = off + (size_t)DENOM * 8 + 64;
    short* pred = (short*)(ws + fixed);

    // k-group: g=4 keeps working set (~172 MB) inside the 256 MB L3 so pred
    // never round-trips HBM (g=8 overflowed: round-4 sim FETCH 199 MB/dispatch).
    int g = 4;
    while (g > 1 && fixed + (size_t)g * pred_k_bytes > ws_size) g >>= 1;

    hipMemsetAsync(col_best, 0, (size_t)DENOM * 8 + 16, stream);
    convert_all<<<2048, 256, 0, stream>>>(encoded_x, context + (size_t)T_IN * B_DIM * L_DIM,
                                          Wk, encbf, ctxbf, wkbf);

    const dim3 g1((STEPS * B_DIM) / 128, 4 * g);    // (206, 4g)
    const dim3 g2(STEPS, 2, g);                     // (103, 2, g)
    for (int k0 = 0; k0 < K_DIM; k0 += g) {
        gemm_bf16<<<g1, 256, 0, stream>>>(ctxbf, wkbf + (size_t)k0 * L_DIM * L_DIM, pred);
        sim_phase<<<g2, 512, 0, stream>>>(encbf, pred, k0, col_best, diag_accum);
    }
    count_correct<<<64, 256, 0, stream>>>(col_best, correct_accum);
    finalize<<<1, 1, 0, stream>>>(correct_accum, diag_accum, out);
}

// Round 7
// 527.680 us; speedup vs baseline: 3.0571x; 1.2292x over previous
//
#include <hip/hip_runtime.h>
#include <math.h>
#include <stdint.h>

// Problem constants (fixed by setup_inputs)
#define S_DIM 128
#define B_DIM 256
#define L_DIM 512
#define K_DIM 8
#define T_IN  16
#define STEPS 103                      // 128 - 16 - (8 + 0 + 1)
#define DENOM (K_DIM * STEPS * B_DIM)  // 210944
#define PRED_K ((size_t)STEPS * B_DIM * L_DIM)   // elems per k slab (13,500,416)

typedef __attribute__((ext_vector_type(8))) short short8;  // 8 bf16 (MFMA A/B frag)
typedef __attribute__((ext_vector_type(4))) float f32x4;   // MFMA C/D frag

// round-to-nearest-even fp32 -> bf16
__device__ __forceinline__ short f2bf(float f) {
    unsigned u = __float_as_uint(f);
    u += 0x7FFFu + ((u >> 16) & 1u);
    return (short)(u >> 16);
}

// async global->LDS, 16B per lane; LDS dest = wave-uniform base + lane*16
__device__ __forceinline__ void load_lds16(const void* g, void* l) {
    __builtin_amdgcn_global_load_lds(
        (const __attribute__((address_space(1))) unsigned*)g,
        (__attribute__((address_space(3))) unsigned*)l, 16, 0, 0);
}

// One fused fp32->bf16 convert over all three inputs (grid-stride, float4)
#define ENC4 ((S_DIM * B_DIM * L_DIM) / 4)          // 4,194,304
#define CTX4 ((STEPS * B_DIM * L_DIM) / 4)          // 3,375,104
#define WK4  ((K_DIM * L_DIM * L_DIM) / 4)          //   524,288
__global__ void convert_all(const float* __restrict__ enc_in, const float* __restrict__ ctx_in,
                            const float* __restrict__ wk_in, short* __restrict__ enc_out,
                            short* __restrict__ ctx_out, short* __restrict__ wk_out) {
    for (int i = blockIdx.x * blockDim.x + threadIdx.x; i < ENC4 + CTX4 + WK4;
         i += gridDim.x * blockDim.x) {
        const float4* src; short4* dst; int j;
        if (i < ENC4)             { src = (const float4*)enc_in; dst = (short4*)enc_out; j = i; }
        else if (i < ENC4 + CTX4) { src = (const float4*)ctx_in; dst = (short4*)ctx_out; j = i - ENC4; }
        else                      { src = (const float4*)wk_in;  dst = (short4*)wk_out;  j = i - ENC4 - CTX4; }
        const float4 v = src[j];
        short4 o;
        o.x = f2bf(v.x); o.y = f2bf(v.y); o.z = f2bf(v.z); o.w = f2bf(v.w);
        dst[j] = o;
    }
}

// ---------------------------------------------------------------------------
// bf16 MFMA GEMM (NT), k-batched, BK=64: grid (206, 4g), bn -> (kin, cn).
// 128x128 tile, 4 waves 2x2, 4x4 16x16x32 frags, 32 MFMA per barrier-pair.
// Staging: 64-elem rows, global_load_lds(16B), XOR chunk swizzle
// ch8 ^ (row&7) (pattern verified round 5 phase A, absmax 0).
// ---------------------------------------------------------------------------
__global__ __launch_bounds__(256)
void gemm_bf16(const short* __restrict__ A, const short* __restrict__ W,
               short* __restrict__ C) {
    __shared__ short As[128 * 64];   // 16 KB
    __shared__ short Bs[128 * 64];   // 16 KB
    const int bm = blockIdx.x;
    const int kin = blockIdx.y >> 2, cn = blockIdx.y & 3;
    const int t = threadIdx.x;
    const int w = t >> 6, lane = t & 63, quad = lane >> 4, l15 = lane & 15;
    const int wm = w & 1, wn = w >> 1;
    const int rl8 = lane >> 3, ch8 = lane & 7;

    const short* Ab = A + (size_t)bm * 128 * L_DIM;
    const short* Wb = W + ((size_t)kin * L_DIM + cn * 128) * L_DIM;
    short* Ck = C + kin * PRED_K;

    f32x4 acc[4][4] = {};

    for (int kt = 0; kt < L_DIM; kt += 64) {
        #pragma unroll
        for (int q = 0; q < 4; q++) {               // 128 rows each of A and B
            const int rb = w * 32 + q * 8;
            const int row = rb + rl8;
            const int ch = ch8 ^ (row & 7);
            load_lds16(Ab + (size_t)row * L_DIM + kt + ch * 8, &As[rb * 64]);
            load_lds16(Wb + (size_t)row * L_DIM + kt + ch * 8, &Bs[rb * 64]);
        }
        __syncthreads();
        #pragma unroll
        for (int k2 = 0; k2 < 2; k2++) {
            short8 a[4], b[4];
            #pragma unroll
            for (int i = 0; i < 4; i++) {
                const int m = wm * 64 + i * 16 + l15;
                a[i] = *(const short8*)&As[m * 64 + ((k2 * 4 + quad) ^ (m & 7)) * 8];
                const int n = wn * 64 + i * 16 + l15;
                b[i] = *(const short8*)&Bs[n * 64 + ((k2 * 4 + quad) ^ (n & 7)) * 8];
            }
            #pragma unroll
            for (int i = 0; i < 4; i++)
                #pragma unroll
                for (int j = 0; j < 4; j++)
                    acc[i][j] = __builtin_amdgcn_mfma_f32_16x16x32_bf16(a[i], b[j], acc[i][j], 0, 0, 0);
        }
        __syncthreads();
    }
    // C/D layout: col = lane&15, row = quad*4 + reg  [verified]
    #pragma unroll
    for (int i = 0; i < 4; i++)
        #pragma unroll
        for (int r = 0; r < 4; r++) {
            const int row = bm * 128 + wm * 64 + i * 16 + quad * 4 + r;
            short* Cr = Ck + (size_t)row * L_DIM + cn * 128 + wn * 64 + l15;
            #pragma unroll
            for (int j = 0; j < 4; j++)
                Cr[j * 16] = f2bf(acc[i][j][r]);
        }
}

// ---------------------------------------------------------------------------
// Fused sim + log-softmax + argmax, k-batched, LDS-staged (m97 cadence).
// Grid (103, 2, g): block (s, bt, kin), rows b = bt*128..+127, cols 0..255.
// 512 thr = 8 waves (mi = w&1, nj = w>>1), wave tile 64x64, 4x4 frags.
// BK=64: stage enc 128x64 (16 KB) + pred 256x64 (32 KB) per iter via
// global_load_lds, 32 MFMA per barrier-pair, 8 iterations.
// acc[i][j][r] = sim[mi*64+i*16+quad*4+r][nj*64+j*16+l15] -- identical layout
// to rounds 4/6, epilogue copied verbatim (verified absmax 0).
// ---------------------------------------------------------------------------
__global__ __launch_bounds__(512)
void sim_phase(const short* __restrict__ encbf, const short* __restrict__ pred,
               const int k0, unsigned long long* __restrict__ col_best,
               float* __restrict__ diag_accum) {
    __shared__ short Es[128 * 64];  // 16 KB
    __shared__ short Ps[256 * 64];  // 32 KB
    __shared__ float rmx[128][4];   // per-(row, nj-wave) max partials
    __shared__ float rsx[128][4];   // per-(row, nj-wave) expsum partials
    __shared__ float dred[8];       // per-wave diag partials
    const int s = blockIdx.x, bt = blockIdx.y, kin = blockIdx.z;
    const int k = k0 + kin;
    const int t = threadIdx.x, w = t >> 6, lane = t & 63;
    const int quad = lane >> 4, l15 = lane & 15;
    const int mi = w & 1, nj = w >> 1;
    const int rl8 = lane >> 3, ch8 = lane & 7;

    const short* Eb = encbf + ((size_t)(T_IN + 1 + k + s) * B_DIM + bt * 128) * L_DIM;
    const short* Pb = pred + kin * PRED_K + (size_t)s * B_DIM * L_DIM;

    f32x4 acc[4][4] = {};

    for (int kt = 0; kt < L_DIM; kt += 64) {
        #pragma unroll
        for (int q = 0; q < 2; q++) {               // Es: 128 rows
            const int rb = w * 16 + q * 8;
            const int row = rb + rl8;
            load_lds16(Eb + (size_t)row * L_DIM + kt + (ch8 ^ (row & 7)) * 8, &Es[rb * 64]);
        }
        #pragma unroll
        for (int q = 0; q < 4; q++) {               // Ps: 256 rows
            const int rb = w * 32 + q * 8;
            const int row = rb + rl8;
            load_lds16(Pb + (size_t)row * L_DIM + kt + (ch8 ^ (row & 7)) * 8, &Ps[rb * 64]);
        }
        __syncthreads();
        #pragma unroll
        for (int k2 = 0; k2 < 2; k2++) {
            short8 a[4], b[4];
            #pragma unroll
            for (int i = 0; i < 4; i++) {
                const int m = mi * 64 + i * 16 + l15;
                a[i] = *(const short8*)&Es[m * 64 + ((k2 * 4 + quad) ^ (m & 7)) * 8];
                const int n = nj * 64 + i * 16 + l15;
                b[i] = *(const short8*)&Ps[n * 64 + ((k2 * 4 + quad) ^ (n & 7)) * 8];
            }
            #pragma unroll
            for (int i = 0; i < 4; i++)
                #pragma unroll
                for (int j = 0; j < 4; j++)
                    acc[i][j] = __builtin_amdgcn_mfma_f32_16x16x32_bf16(a[i], b[j], acc[i][j], 0, 0, 0);
        }
        __syncthreads();
    }

    // ---- E1: row max over 256 cols ----
    float rm[4][4];
    #pragma unroll
    for (int i = 0; i < 4; i++)
        #pragma unroll
        for (int r = 0; r < 4; r++) {
            float m = acc[i][0][r];
            #pragma unroll
            for (int j = 1; j < 4; j++) m = fmaxf(m, acc[i][j][r]);
            rm[i][r] = m;
        }
    #pragma unroll
    for (int off = 1; off < 16; off <<= 1)
        #pragma unroll
        for (int i = 0; i < 4; i++)
            #pragma unroll
            for (int r = 0; r < 4; r++)
                rm[i][r] = fmaxf(rm[i][r], __shfl_xor(rm[i][r], off, 64));
    if (l15 == 0)
        #pragma unroll
        for (int i = 0; i < 4; i++)
            #pragma unroll
            for (int r = 0; r < 4; r++)
                rmx[mi * 64 + i * 16 + quad * 4 + r][nj] = rm[i][r];
    __syncthreads();

    float mrow[4][4];
    #pragma unroll
    for (int i = 0; i < 4; i++)
        #pragma unroll
        for (int r = 0; r < 4; r++) {
            const f32x4 v = *(const f32x4*)rmx[mi * 64 + i * 16 + quad * 4 + r];
            mrow[i][r] = fmaxf(fmaxf(v[0], v[1]), fmaxf(v[2], v[3]));
        }

    // ---- E2: row sum of exp ----
    float rs[4][4];
    #pragma unroll
    for (int i = 0; i < 4; i++)
        #pragma unroll
        for (int r = 0; r < 4; r++) {
            float sum = 0.f;
            #pragma unroll
            for (int j = 0; j < 4; j++) sum += expf(acc[i][j][r] - mrow[i][r]);
            rs[i][r] = sum;
        }
    #pragma unroll
    for (int off = 1; off < 16; off <<= 1)
        #pragma unroll
        for (int i = 0; i < 4; i++)
            #pragma unroll
            for (int r = 0; r < 4; r++)
                rs[i][r] += __shfl_xor(rs[i][r], off, 64);
    if (l15 == 0)
        #pragma unroll
        for (int i = 0; i < 4; i++)
            #pragma unroll
            for (int r = 0; r < 4; r++)
                rsx[mi * 64 + i * 16 + quad * 4 + r][nj] = rs[i][r];
    __syncthreads();

    float lse[4][4];
    #pragma unroll
    for (int i = 0; i < 4; i++)
        #pragma unroll
        for (int r = 0; r < 4; r++) {
            const f32x4 v = *(const f32x4*)rsx[mi * 64 + i * 16 + quad * 4 + r];
            lse[i][r] = mrow[i][r] + logf(v[0] + v[1] + v[2] + v[3]);
        }

    // ---- E3: column argmax (packed u64: ordered-float<<32 | (255-b)) ----
    #pragma unroll
    for (int j = 0; j < 4; j++) {
        unsigned long long best = 0;
        #pragma unroll
        for (int i = 0; i < 4; i++)
            #pragma unroll
            for (int r = 0; r < 4; r++) {
                const int grow = bt * 128 + mi * 64 + i * 16 + quad * 4 + r;
                const float v = acc[i][j][r] - lse[i][r];
                unsigned int fb = __float_as_uint(v);
                fb = (fb & 0x80000000u) ? ~fb : (fb | 0x80000000u);
                const unsigned long long p =
                    ((unsigned long long)fb << 32) | (unsigned long long)(255 - grow);
                if (p > best) best = p;          // packed compare: ties -> smallest b
            }
        unsigned long long o;
        o = __shfl_xor(best, 16, 64); if (o > best) best = o;
        o = __shfl_xor(best, 32, 64); if (o > best) best = o;
        if (quad == 0)
            atomicMax(&col_best[((size_t)k * STEPS + s) * B_DIM + nj * 64 + j * 16 + l15], best);
    }

    // ---- diag logp: 1 atomic per block ----
    {
        float dv = 0.f;
        #pragma unroll
        for (int i = 0; i < 4; i++)
            #pragma unroll
            for (int j = 0; j < 4; j++)
                #pragma unroll
                for (int r = 0; r < 4; r++) {
                    const int grow = bt * 128 + mi * 64 + i * 16 + quad * 4 + r;
                    const int c = nj * 64 + j * 16 + l15;
                    if (grow == c) dv += acc[i][j][r] - lse[i][r];
                }
        #pragma unroll
        for (int off = 1; off < 64; off <<= 1) dv += __shfl_xor(dv, off, 64);
        if (lane == 0) dred[w] = dv;
    }
    __syncthreads();
    if (t == 0) {
        float dv = 0.f;
        #pragma unroll
        for (int i = 0; i < 8; i++) dv += dred[i];
        atomicAdd(diag_accum, dv);
    }
}

__global__ void count_correct(const unsigned long long* __restrict__ col_best,
                              int* __restrict__ correct_accum) {
    __shared__ int red[256];
    const int t = threadIdx.x;
    int cnt = 0;
    for (int i = blockIdx.x * 256 + t; i < DENOM; i += gridDim.x * 256) {
        const int c = i & (B_DIM - 1);
        const int b = 255 - (int)(col_best[i] & 0xFFFFFFFFull);
        cnt += (b == c) ? 1 : 0;
    }
    red[t] = cnt;
    __syncthreads();
    for (int off = 128; off > 0; off >>= 1) {
        if (t < off) red[t] += red[t + off];
        __syncthreads();
    }
    if (t == 0) atomicAdd(correct_accum, red[0]);
}

__global__ void finalize(const int* __restrict__ correct_accum,
                         const float* __restrict__ diag_accum,
                         float* __restrict__ out) {
    const float denom = (float)DENOM;
    out[0] = (float)(*correct_accum) / denom;   // accuracy
    out[1] = -(*diag_accum) / denom;            // loss
}

extern "C" void kernel_launch(void* const* d_in, const int* in_sizes, int n_in,
                              void* d_out, int out_size, void* d_ws, size_t ws_size,
                              hipStream_t stream) {
    const float* encoded_x = (const float*)d_in[0];
    const float* context   = (const float*)d_in[1];
    const float* Wk        = (const float*)d_in[2];
    float* out = (float*)d_out;

    const size_t enc_elems = (size_t)S_DIM * B_DIM * L_DIM;    // 16,777,216
    const size_t ctx_elems = (size_t)STEPS * B_DIM * L_DIM;    // 13,500,416
    const size_t wk_elems  = (size_t)K_DIM * L_DIM * L_DIM;    //  2,097,152
    const size_t pred_k_bytes = ctx_elems * 2;                 // 27.0 MB per k

    char* ws = (char*)d_ws;
    short* encbf = (short*)ws;                                          // 33.6 MB
    short* ctxbf = (short*)(ws + enc_elems * 2);                        // 27.0 MB
    short* wkbf  = (short*)(ws + (enc_elems + ctx_elems) * 2);          //  4.2 MB
    const size_t off = (enc_elems + ctx_elems + wk_elems) * 2;
    unsigned long long* col_best = (unsigned long long*)(ws + off);     // 1.69 MB
    float* diag_accum    = (float*)(ws + off + (size_t)DENOM * 8);
    int*   correct_accum = (int*)  (ws + off + (size_t)DENOM * 8 + 4);
    const size_t fixed = off + (size_t)DENOM * 8 + 64;
    short* pred = (short*)(ws + fixed);

    // g=8: single gemm + single sim dispatch. Sim is latency-bound, not
    // BW-bound (r6: 1.0 TB/s, MfmaUtil 5.7%) -- maximize per-dispatch waves.
    int g = K_DIM;
    while (g > 1 && fixed + (size_t)g * pred_k_bytes > ws_size) g >>= 1;

    hipMemsetAsync(col_best, 0, (size_t)DENOM * 8 + 16, stream);
    convert_all<<<2048, 256, 0, stream>>>(encoded_x, context + (size_t)T_IN * B_DIM * L_DIM,
                                          Wk, encbf, ctxbf, wkbf);

    const dim3 g1((STEPS * B_DIM) / 128, 4 * g);    // (206, 4g)
    const dim3 g2(STEPS, 2, g);                     // (103, 2, g)
    for (int k0 = 0; k0 < K_DIM; k0 += g) {
        gemm_bf16<<<g1, 256, 0, stream>>>(ctxbf, wkbf + (size_t)k0 * L_DIM * L_DIM, pred);
        sim_phase<<<g2, 512, 0, stream>>>(encbf, pred, k0, col_best, diag_accum);
    }
    count_correct<<<64, 256, 0, stream>>>(col_best, correct_accum);
    finalize<<<1, 1, 0, stream>>>(correct_accum, diag_accum, out);
}